// Round 1
// baseline (516.082 us; speedup 1.0000x reference)
//
#include <hip/hip_runtime.h>
#include <hip/hip_bf16.h>
#include <math.h>

#define C_DIM 128
#define B_DIM 4
#define N_DIM 8192
#define M_DIM 2048

typedef unsigned short u16;
typedef unsigned int u32;

// Per guide §3: gfx950 bf16 MFMA fragment = 8 x short (4 VGPRs)
typedef short bf16x8 __attribute__((ext_vector_type(8)));
typedef float f32x4 __attribute__((ext_vector_type(4)));

__device__ inline u16 f2bf(float f) {
  u32 u = __builtin_bit_cast(u32, f);
  u += 0x7fffu + ((u >> 16) & 1u);  // RNE; inputs are finite normals
  return (u16)(u >> 16);
}

// MODE 0: bf16 transposed out[x][o]  (Qt, Kt)
// MODE 1: f32  out[o][x]             (skip -> d_out)
// MODE 2: bf16 out[o][x]             (V)
template <int MODE>
__global__ __launch_bounds__(256) void proj_kernel(
    const float* __restrict__ in, const float* __restrict__ W,
    void* __restrict__ out, int X, float scale) {
  __shared__ float tile[128][65];
  const int b = blockIdx.y;
  const int x0 = blockIdx.x * 64;
  const int t = threadIdx.x;
  const float* inb = in + (size_t)b * C_DIM * X;

  #pragma unroll
  for (int i = 0; i < 32; ++i) {           // load [c][j] tile, coalesced over j
    int idx = t + 256 * i;
    int c = idx >> 6, j = idx & 63;
    tile[c][j] = inb[(size_t)c * X + x0 + j];
  }
  __syncthreads();

  const int w = t >> 6, j = t & 63;        // wave w owns 32 output channels
  float acc[32];
  #pragma unroll
  for (int oi = 0; oi < 32; ++oi) acc[oi] = 0.f;
  for (int c = 0; c < 128; ++c) {
    float xv = tile[c][j];                 // 1 ds_read, broadcast-free (lanes vary j)
    #pragma unroll
    for (int oi = 0; oi < 32; ++oi)        // W index wave-uniform -> s_loads
      acc[oi] += W[(w * 32 + oi) * 128 + c] * xv;
  }

  if (MODE == 0) {
    union { u16 u[32]; uint4 v[4]; } pk;
    #pragma unroll
    for (int oi = 0; oi < 32; ++oi) pk.u[oi] = f2bf(acc[oi] * scale);
    uint4* dst = (uint4*)((u16*)out + ((size_t)b * X + x0 + j) * 128 + w * 32);
    #pragma unroll
    for (int q = 0; q < 4; ++q) dst[q] = pk.v[q];   // 64B contiguous per thread
  } else {
    __syncthreads();                       // reuse tile as [o][j] (all reads done)
    #pragma unroll
    for (int oi = 0; oi < 32; ++oi) tile[w * 32 + oi][j] = acc[oi] * scale;
    __syncthreads();
    #pragma unroll
    for (int i = 0; i < 32; ++i) {         // coalesced store over x
      int idx = t + 256 * i;
      int o = idx >> 6, j2 = idx & 63;
      if (MODE == 1)
        ((float*)out)[(size_t)b * C_DIM * X + (size_t)o * X + x0 + j2] = tile[o][j2];
      else
        ((u16*)out)[(size_t)b * C_DIM * X + (size_t)o * X + x0 + j2] = f2bf(tile[o][j2]);
    }
  }
}

// Flash attention: block = (64 q-rows, batch b), 4 waves x 16 q-rows each.
// Qt [B][N][C] bf16 (pre-scaled by log2e/sqrt(C)); Kt [B][M][C] bf16; V [B][C][M] bf16.
// out already holds skip (f32); we += the attention output.
__global__ __launch_bounds__(256) void attn_kernel(
    const u16* __restrict__ Qt, const u16* __restrict__ Kt,
    const u16* __restrict__ Vw, float* __restrict__ out) {
  __shared__ union {
    struct {
      u16 k[64 * 128];     // [m][c], XOR-swizzled 16B chunks
      u16 v[128 * 64];     // [c][m], XOR-swizzled
      u16 p[4][16 * 64];   // per-wave P tile, XOR-swizzled
    } s;
    float ot[64 * 133];    // epilogue transpose buffer
  } lds;

  const int b = blockIdx.y;
  const int n0 = blockIdx.x * 64;
  const int t = threadIdx.x;
  const int w = t >> 6;
  const int l = t & 63;
  const int lr = l & 15;
  const int lh = l >> 4;

  // Q fragments: A[i][k], i = l&15 (q-row), k = 8*(l>>4)+b_ + 32*kc (channel)
  bf16x8 qf[4];
  {
    const u16* qp = Qt + ((size_t)b * N_DIM + n0 + w * 16 + lr) * 128 + lh * 8;
    #pragma unroll
    for (int kc = 0; kc < 4; ++kc) qf[kc] = *(const bf16x8*)(qp + kc * 32);
  }

  f32x4 acco[8];
  #pragma unroll
  for (int ct = 0; ct < 8; ++ct) acco[ct] = 0.f;
  float mrow[4], lrow[4];
  #pragma unroll
  for (int r = 0; r < 4; ++r) { mrow[r] = -INFINITY; lrow[r] = 0.f; }

  const uint4* kg = (const uint4*)(Kt + (size_t)b * M_DIM * 128);
  const uint4* vg = (const uint4*)(Vw + (size_t)b * 128 * M_DIM);

  for (int m0 = 0; m0 < M_DIM; m0 += 64) {
    __syncthreads();  // previous tile's LDS reads complete
    {
      uint4* kl = (uint4*)lds.s.k;
      uint4* vl = (uint4*)lds.s.v;
      #pragma unroll
      for (int i = 0; i < 4; ++i) {  // K: 64 rows x 16 chunks
        int ch = t + 256 * i;
        int row = ch >> 4, c8 = ch & 15;
        kl[row * 16 + (c8 ^ (row & 7))] = kg[((m0 + row) << 4) + c8];
      }
      #pragma unroll
      for (int i = 0; i < 4; ++i) {  // V: 128 rows x 8 chunks
        int ch = t + 256 * i;
        int c = ch >> 3, m8 = ch & 7;
        vl[c * 8 + (m8 ^ (c & 7))] = vg[(size_t)c * (M_DIM / 8) + (m0 >> 3) + m8];
      }
    }
    __syncthreads();

    // S = Q·K^T for this wave's 16 q-rows x 64 m-cols
    f32x4 sacc[4];
    #pragma unroll
    for (int mt = 0; mt < 4; ++mt) sacc[mt] = 0.f;
    #pragma unroll
    for (int kc = 0; kc < 4; ++kc) {
      #pragma unroll
      for (int mt = 0; mt < 4; ++mt) {
        int row = mt * 16 + lr;  // B[k][j]: j=l&15 -> m-row of Kt
        int idx = (row * 128 + kc * 32 + lh * 8) ^ ((row & 7) << 3);
        bf16x8 kf = *(const bf16x8*)&lds.s.k[idx];
        sacc[mt] = __builtin_amdgcn_mfma_f32_16x16x32_bf16(qf[kc], kf, sacc[mt], 0, 0, 0);
      }
    }

    // Online softmax. Lane holds S[qi][mi], qi = lh*4+r, mi = mt*16+lr.
    float sc[4];
    u16 pb[4][4];
    #pragma unroll
    for (int r = 0; r < 4; ++r) {
      float v0 = fmaxf(fmaxf(sacc[0][r], sacc[1][r]), fmaxf(sacc[2][r], sacc[3][r]));
      #pragma unroll
      for (int off = 8; off; off >>= 1) v0 = fmaxf(v0, __shfl_xor(v0, off, 64));
      float mn = fmaxf(mrow[r], v0);
      sc[r] = exp2f(mrow[r] - mn);   // 0 on first tile (-inf - finite)
      mrow[r] = mn;
      float rs = 0.f;
      #pragma unroll
      for (int mt = 0; mt < 4; ++mt) {
        float p = exp2f(sacc[mt][r] - mn);
        rs += p;
        pb[mt][r] = f2bf(p);
      }
      #pragma unroll
      for (int off = 8; off; off >>= 1) rs += __shfl_xor(rs, off, 64);
      lrow[r] = lrow[r] * sc[r] + rs;
    }
    #pragma unroll
    for (int ct = 0; ct < 8; ++ct)
      #pragma unroll
      for (int r = 0; r < 4; ++r) acco[ct][r] *= sc[r];

    // P round-trip through wave-private LDS to re-fragment for PV
    u16* pl = lds.s.p[w];
    #pragma unroll
    for (int mt = 0; mt < 4; ++mt)
      #pragma unroll
      for (int r = 0; r < 4; ++r) {
        int row = lh * 4 + r, cc = mt * 16 + lr;
        int sidx = row * 64 + ((((cc >> 3) ^ (row & 7)) << 3) | (cc & 7));
        pl[sidx] = pb[mt][r];
      }
    asm volatile("s_waitcnt lgkmcnt(0)" ::: "memory");  // wave-internal cross-lane

    // O += P·V^T : A = P[qi][m], B = V[c][m] rows give B[k=m][j=c]
    #pragma unroll
    for (int kc2 = 0; kc2 < 2; ++kc2) {
      int pidx = lr * 64 + (((kc2 * 4 + lh) ^ (lr & 7)) << 3);
      bf16x8 pf = *(const bf16x8*)&pl[pidx];
      #pragma unroll
      for (int ct = 0; ct < 8; ++ct) {
        int vrow = ct * 16 + lr;
        int vidx = vrow * 64 + (((kc2 * 4 + lh) ^ (vrow & 7)) << 3);
        bf16x8 vf = *(const bf16x8*)&lds.s.v[vidx];
        acco[ct] = __builtin_amdgcn_mfma_f32_16x16x32_bf16(pf, vf, acco[ct], 0, 0, 0);
      }
    }
  }

  __syncthreads();  // all tile-loop LDS traffic done; reuse as f32 transpose buf
  #pragma unroll
  for (int r = 0; r < 4; ++r) {
    float inv = 1.f / lrow[r];
    #pragma unroll
    for (int ct = 0; ct < 8; ++ct) acco[ct][r] *= inv;
  }
  #pragma unroll
  for (int ct = 0; ct < 8; ++ct)
    #pragma unroll
    for (int r = 0; r < 4; ++r) {
      int q = w * 16 + lh * 4 + r;
      int c = ct * 16 + lr;
      lds.ot[q * 133 + c] = acco[ct][r];
    }
  __syncthreads();
  float* ob = out + (size_t)b * C_DIM * N_DIM + n0;
  #pragma unroll
  for (int i = 0; i < 32; ++i) {  // coalesced over n; += skip already in d_out
    int idx = t + 256 * i;
    int cc = idx >> 6, q = idx & 63;
    ob[(size_t)cc * N_DIM + q] += lds.ot[q * 133 + cc];
  }
}

extern "C" void kernel_launch(void* const* d_in, const int* in_sizes, int n_in,
                              void* d_out, int out_size, void* d_ws, size_t ws_size,
                              hipStream_t stream) {
  const float* up    = (const float*)d_in[0];
  const float* down  = (const float*)d_in[1];
  const float* wq    = (const float*)d_in[2];
  const float* wk    = (const float*)d_in[3];
  const float* wv    = (const float*)d_in[4];
  const float* wskip = (const float*)d_in[5];
  float* out = (float*)d_out;

  u16* Qt = (u16*)d_ws;                                   // 8 MB
  u16* Kt = Qt + (size_t)B_DIM * N_DIM * C_DIM;           // 2 MB
  u16* Vw = Kt + (size_t)B_DIM * M_DIM * C_DIM;           // 2 MB

  const float qscale = (float)(1.4426950408889634 / sqrt(128.0));  // log2e/sqrt(C)
  dim3 blk(256);
  hipLaunchKernelGGL((proj_kernel<0>), dim3(N_DIM / 64, B_DIM), blk, 0, stream,
                     up, wq, (void*)Qt, N_DIM, qscale);
  hipLaunchKernelGGL((proj_kernel<0>), dim3(M_DIM / 64, B_DIM), blk, 0, stream,
                     down, wk, (void*)Kt, M_DIM, 1.f);
  hipLaunchKernelGGL((proj_kernel<2>), dim3(M_DIM / 64, B_DIM), blk, 0, stream,
                     down, wv, (void*)Vw, M_DIM, 1.f);
  hipLaunchKernelGGL((proj_kernel<1>), dim3(N_DIM / 64, B_DIM), blk, 0, stream,
                     up, wskip, (void*)d_out, N_DIM, 1.f);
  hipLaunchKernelGGL((attn_kernel), dim3(N_DIM / 64, B_DIM), blk, 0, stream,
                     Qt, Kt, Vw, out);
}

// Round 2
// 133.357 us; speedup vs baseline: 3.8699x; 3.8699x over previous
//
#include <hip/hip_runtime.h>
#include <hip/hip_bf16.h>
#include <math.h>

#define C_DIM 128
#define B_DIM 4
#define N_DIM 8192
#define M_DIM 2048
#define NT_KV 32   // M_DIM / 64 KV tiles

typedef unsigned short u16;
typedef unsigned int u32;
typedef short bf16x8 __attribute__((ext_vector_type(8)));
typedef float f32x4 __attribute__((ext_vector_type(4)));
typedef float f32x16 __attribute__((ext_vector_type(16)));
typedef u32 u32x4 __attribute__((ext_vector_type(4)));

__device__ inline u16 f2bf(float f) {
  u32 u = __builtin_bit_cast(u32, f);
  u += 0x7fffu + ((u >> 16) & 1u);  // RNE, finite inputs
  return (u16)(u >> 16);
}
__device__ inline u32 cvtpk_bf16(float lo, float hi) {
  u32 r;
  asm("v_cvt_pk_bf16_f32 %0, %1, %2" : "=v"(r) : "v"(lo), "v"(hi));
  return r;
}

// ---------------- Projections: Y = W @ X_b, MFMA 16x16x32 ----------------
// Block: 256 thr = 4 waves; x-tile 64; wave w owns o in [w*32, w*32+32).
// MODE 0: Qt bf16 [b][x][o]         (row-major over o -> attn q-frag loads)
// MODE 1: skip f32 [b][o][x]        (straight into d_out)
// MODE 2: K frag-major for attn     (linear-copy stageable)
// MODE 3: V frag-major for attn
template <int MODE>
__device__ inline void proj_pass(const float* __restrict__ W, float wscale,
                                 const u16* __restrict__ xt_s,
                                 float* __restrict__ outf, u16* __restrict__ outh,
                                 int b, int X, int x0, int t) {
  const int l = t & 63, w = t >> 6, lr = l & 15, lh = (l >> 4) & 3;
  // W fragments, register resident: A[i=o][k=c], o = w*32+ot*16+lr, c = kc*32+lh*8+e
  bf16x8 wf[2][4];
  #pragma unroll
  for (int ot = 0; ot < 2; ++ot)
    #pragma unroll
    for (int kc = 0; kc < 4; ++kc) {
      const float* wp = &W[(size_t)(w * 32 + ot * 16 + lr) * 128 + kc * 32 + lh * 8];
      float4 a0 = *(const float4*)wp;
      float4 a1 = *(const float4*)(wp + 4);
      bf16x8 f;
      f[0] = (short)f2bf(a0.x * wscale); f[1] = (short)f2bf(a0.y * wscale);
      f[2] = (short)f2bf(a0.z * wscale); f[3] = (short)f2bf(a0.w * wscale);
      f[4] = (short)f2bf(a1.x * wscale); f[5] = (short)f2bf(a1.y * wscale);
      f[6] = (short)f2bf(a1.z * wscale); f[7] = (short)f2bf(a1.w * wscale);
      wf[ot][kc] = f;
    }
  f32x4 acc[2][4];
  #pragma unroll
  for (int ot = 0; ot < 2; ++ot)
    #pragma unroll
    for (int xt = 0; xt < 4; ++xt) acc[ot][xt] = 0.f;

  #pragma unroll
  for (int xt = 0; xt < 4; ++xt) {
    int xx = xt * 16 + lr;
    #pragma unroll
    for (int kc = 0; kc < 4; ++kc) {
      // B[k=c][j=x] from transposed-swizzled Xt
      bf16x8 bf = *(const bf16x8*)&xt_s[xx * 128 + ((kc * 32 + lh * 8) ^ ((xx & 15) << 3))];
      #pragma unroll
      for (int ot = 0; ot < 2; ++ot)
        acc[ot][xt] = __builtin_amdgcn_mfma_f32_16x16x32_bf16(wf[ot][kc], bf, acc[ot][xt], 0, 0, 0);
    }
  }
  // D: col = l&15 = x, row = lh*4 + r = o-within-16
  #pragma unroll
  for (int ot = 0; ot < 2; ++ot) {
    int o0 = w * 32 + ot * 16 + lh * 4;
    #pragma unroll
    for (int xt = 0; xt < 4; ++xt) {
      int xg = x0 + xt * 16 + lr;
      if constexpr (MODE == 0) {
        u16 h[4];
        #pragma unroll
        for (int r = 0; r < 4; ++r) h[r] = f2bf(acc[ot][xt][r]);
        *(uint2*)&outh[((size_t)b * X + xg) * 128 + o0] = *(uint2*)h;
      } else if constexpr (MODE == 1) {
        #pragma unroll
        for (int r = 0; r < 4; ++r)
          outf[((size_t)b * 128 + o0 + r) * X + xg] = acc[ot][xt][r];
      } else if constexpr (MODE == 2) {
        // K[m=xg][c=o0..o0+3] -> frag (t64, mt, kcK), slot = (m&31)|(lh1<<5), elem = c&7
        int tt = xg >> 6, mt = (xg >> 5) & 1, ms = xg & 31;
        int kcK = o0 >> 4, lh1p = (o0 >> 3) & 1, e0 = o0 & 7;
        u16 h[4];
        #pragma unroll
        for (int r = 0; r < 4; ++r) h[r] = f2bf(acc[ot][xt][r]);
        size_t off = ((((size_t)(b * NT_KV + tt) * 2 + mt) * 8 + kcK) * 64 + (ms | (lh1p << 5))) * 8 + e0;
        *(uint2*)&outh[off] = *(uint2*)h;
      } else {
        // V[c=o0+r][m=xg] -> frag (t64, ct, s), slot = (c&31)|(lh1m<<5), elem = m&7
        int tt = xg >> 6, sv = (xg >> 4) & 3, lh1m = (xg >> 3) & 1, e = xg & 7;
        int ctv = o0 >> 5;
        #pragma unroll
        for (int r = 0; r < 4; ++r) {
          int cs = (o0 + r) & 31;
          size_t off = ((((size_t)(b * NT_KV + tt) * 4 + ctv) * 4 + sv) * 64 + (cs | (lh1m << 5))) * 8 + e;
          outh[off] = f2bf(acc[ot][xt][r]);
        }
      }
    }
  }
}

template <int MODE_A, int MODE_B>
__global__ __launch_bounds__(256, 2) void proj_kernel(
    const float* __restrict__ in, const float* __restrict__ WA, const float* __restrict__ WB,
    float* __restrict__ fA, u16* __restrict__ hA, float* __restrict__ fB, u16* __restrict__ hB,
    int X, float wscaleA) {
  __shared__ u16 xt_s[64 * 128];  // [x][c] bf16, c XOR-swizzled by (x&15)<<3
  const int b = blockIdx.y, x0 = blockIdx.x * 64, t = threadIdx.x;
  #pragma unroll
  for (int pp = 0; pp < 8; ++pp) {
    int c = pp * 16 + (t >> 4);
    int x4 = (t & 15) * 4;
    float4 v = *(const float4*)&in[((size_t)b * 128 + c) * X + x0 + x4];
    xt_s[(x4 + 0) * 128 + (c ^ (((x4 + 0) & 15) << 3))] = f2bf(v.x);
    xt_s[(x4 + 1) * 128 + (c ^ (((x4 + 1) & 15) << 3))] = f2bf(v.y);
    xt_s[(x4 + 2) * 128 + (c ^ (((x4 + 2) & 15) << 3))] = f2bf(v.z);
    xt_s[(x4 + 3) * 128 + (c ^ (((x4 + 3) & 15) << 3))] = f2bf(v.w);
  }
  __syncthreads();
  proj_pass<MODE_A>(WA, wscaleA, xt_s, fA, hA, b, X, x0, t);
  proj_pass<MODE_B>(WB, 1.0f, xt_s, fB, hB, b, X, x0, t);
}

// ---------------- Flash attention, 32x32x16, swapped QK^T ----------------
__device__ inline void stage_kv(const u16* __restrict__ gK, const u16* __restrict__ gV,
                                u16* lK, u16* lV, int tile, int t) {
  const u16* ks = gK + (size_t)tile * 8192;
  const u16* vs = gV + (size_t)tile * 8192;
  #pragma unroll
  for (int i = 0; i < 4; ++i) {
    int ch = t + i * 256;
    __builtin_amdgcn_global_load_lds((const __attribute__((address_space(1))) void*)(ks + ch * 8),
                                     (__attribute__((address_space(3))) void*)(lK + ch * 8), 16, 0, 0);
    __builtin_amdgcn_global_load_lds((const __attribute__((address_space(1))) void*)(vs + ch * 8),
                                     (__attribute__((address_space(3))) void*)(lV + ch * 8), 16, 0, 0);
  }
}

__global__ __launch_bounds__(256, 1) void attn_kernel(
    const u16* __restrict__ Qt, const u16* __restrict__ Kt2,
    const u16* __restrict__ Vp, float* __restrict__ out) {
  __shared__ alignas(16) u16 kbuf[2][8192];
  __shared__ alignas(16) u16 vbuf[2][8192];
  const int bid = blockIdx.x;
  const int xcd = bid & 7, b = xcd & 3, slot = bid >> 3;     // XCD-affine: one batch per L2
  const int n0 = ((xcd >> 2) * 32 + slot) * 128;
  const int t = threadIdx.x, w = t >> 6, l = t & 63, lh1 = l >> 5;
  const int nq = n0 + w * 32 + (l & 31);

  // Q fragments (B[k=c][j=q]): resident. q = l&31, c = kc*16 + lh1*8 + e
  bf16x8 qf[8];
  #pragma unroll
  for (int kc = 0; kc < 8; ++kc)
    qf[kc] = *(const bf16x8*)&Qt[((size_t)b * N_DIM + nq) * 128 + kc * 16 + lh1 * 8];

  const u16* gK = Kt2 + (size_t)b * NT_KV * 8192;
  const u16* gV = Vp + (size_t)b * NT_KV * 8192;

  f32x16 acco[4];
  #pragma unroll
  for (int ct = 0; ct < 4; ++ct) acco[ct] = 0.f;
  float mrun = -INFINITY, lrun = 0.f;

  stage_kv(gK, gV, kbuf[0], vbuf[0], 0, t);
  __syncthreads();
  int cur = 0;
  for (int tt = 0; tt < NT_KV; ++tt) {
    if (tt + 1 < NT_KV) stage_kv(gK, gV, kbuf[cur ^ 1], vbuf[cur ^ 1], tt + 1, t);
    const u16* lK = kbuf[cur];
    const u16* lV = vbuf[cur];

    // S[m][q] = sum_c K[m][c] Q[q][c]; lane-linear frag reads (conflict-free)
    f32x16 sacc[2];
    sacc[0] = 0.f; sacc[1] = 0.f;
    #pragma unroll
    for (int kc = 0; kc < 8; ++kc)
      #pragma unroll
      for (int mt = 0; mt < 2; ++mt) {
        bf16x8 kf = *(const bf16x8*)&lK[((mt * 8 + kc) * 64 + l) * 8];
        sacc[mt] = __builtin_amdgcn_mfma_f32_32x32x16_bf16(kf, qf[kc], sacc[mt], 0, 0, 0);
      }

    // Online softmax: lane holds 32 of 64 m for q=l&31; partner l^32 holds rest.
    float pm = sacc[0][0];
    #pragma unroll
    for (int mt = 0; mt < 2; ++mt)
      #pragma unroll
      for (int r = 0; r < 16; ++r) pm = fmaxf(pm, sacc[mt][r]);
    pm = fmaxf(pm, __shfl_xor(pm, 32, 64));
    if (!__all(pm <= mrun + 11.0f)) {   // defer-max (T13): skip rescale on small growth
      float mn = fmaxf(mrun, pm);
      float sc = exp2f(mrun - mn);      // 0 on first tile
      lrun *= sc;
      #pragma unroll
      for (int ct = 0; ct < 4; ++ct)
        #pragma unroll
        for (int r = 0; r < 16; ++r) acco[ct][r] *= sc;
      mrun = mn;
    }
    float p[2][16];
    float rs = 0.f;
    #pragma unroll
    for (int mt = 0; mt < 2; ++mt)
      #pragma unroll
      for (int r = 0; r < 16; ++r) {
        p[mt][r] = exp2f(sacc[mt][r] - mrun);
        rs += p[mt][r];
      }
    rs += __shfl_xor(rs, 32, 64);
    lrun += rs;

    // Pack P groups-of-4 consecutive m: G[mt*4+j] base m = mt*32 + 8j + 4*lh1
    u32 g[8][2];
    #pragma unroll
    for (int mt = 0; mt < 2; ++mt)
      #pragma unroll
      for (int j = 0; j < 4; ++j) {
        g[mt * 4 + j][0] = cvtpk_bf16(p[mt][j * 4 + 0], p[mt][j * 4 + 1]);
        g[mt * 4 + j][1] = cvtpk_bf16(p[mt][j * 4 + 2], p[mt][j * 4 + 3]);
      }
    // PV: O[c][q] += V[c][m] P[m][q]; B-frag needs m = s*16 + 8*lh1 + 0..7
    #pragma unroll
    for (int s = 0; s < 4; ++s) {
      const int ga = (s >> 1) * 4 + (s & 1) * 2, gb = ga + 1;
      u32 s0 = lh1 ? g[ga][0] : g[gb][0];   // send what partner needs
      u32 s1 = lh1 ? g[ga][1] : g[gb][1];
      u32 r0 = (u32)__shfl_xor((int)s0, 32, 64);
      u32 r1 = (u32)__shfl_xor((int)s1, 32, 64);
      u32x4 fv;
      fv.x = lh1 ? r0 : g[ga][0];
      fv.y = lh1 ? r1 : g[ga][1];
      fv.z = lh1 ? g[gb][0] : r0;
      fv.w = lh1 ? g[gb][1] : r1;
      bf16x8 pf = __builtin_bit_cast(bf16x8, fv);
      #pragma unroll
      for (int ct = 0; ct < 4; ++ct) {
        bf16x8 vf = *(const bf16x8*)&lV[((ct * 4 + s) * 64 + l) * 8];
        acco[ct] = __builtin_amdgcn_mfma_f32_32x32x16_bf16(vf, pf, acco[ct], 0, 0, 0);
      }
    }
    __syncthreads();  // drains prefetch (vmcnt) + protects dbuf swap
    cur ^= 1;
  }

  // Epilogue: O[c][q]/l + skip (already in d_out)
  float invl = 1.0f / lrun;
  #pragma unroll
  for (int ct = 0; ct < 4; ++ct)
    #pragma unroll
    for (int r = 0; r < 16; ++r) {
      int c = ct * 32 + (r & 3) + 8 * ((r >> 2) & 3) + 4 * lh1;
      out[((size_t)b * 128 + c) * N_DIM + nq] += acco[ct][r] * invl;
    }
}

extern "C" void kernel_launch(void* const* d_in, const int* in_sizes, int n_in,
                              void* d_out, int out_size, void* d_ws, size_t ws_size,
                              hipStream_t stream) {
  const float* up    = (const float*)d_in[0];
  const float* down  = (const float*)d_in[1];
  const float* wq    = (const float*)d_in[2];
  const float* wk    = (const float*)d_in[3];
  const float* wv    = (const float*)d_in[4];
  const float* wskip = (const float*)d_in[5];
  float* out = (float*)d_out;

  u16* Qt  = (u16*)d_ws;                                   // 8 MB  [b][n][c]
  u16* Kt2 = Qt + (size_t)B_DIM * N_DIM * C_DIM;           // 2 MB  frag-major
  u16* Vp  = Kt2 + (size_t)B_DIM * M_DIM * C_DIM;          // 2 MB  frag-major

  const float qscale = (float)(1.4426950408889634 / sqrt(128.0));  // log2e/sqrt(C)

  hipLaunchKernelGGL((proj_kernel<0, 1>), dim3(N_DIM / 64, B_DIM), dim3(256), 0, stream,
                     up, wq, wskip, nullptr, Qt, out, nullptr, N_DIM, qscale);
  hipLaunchKernelGGL((proj_kernel<2, 3>), dim3(M_DIM / 64, B_DIM), dim3(256), 0, stream,
                     down, wk, wv, nullptr, Kt2, nullptr, Vp, M_DIM, 1.0f);
  hipLaunchKernelGGL((attn_kernel), dim3(256), dim3(256), 0, stream,
                     Qt, Kt2, Vp, out);
}

// Round 3
// 100.240 us; speedup vs baseline: 5.1485x; 1.3304x over previous
//
#include <hip/hip_runtime.h>
#include <hip/hip_bf16.h>
#include <math.h>

#define C_DIM 128
#define B_DIM 4
#define N_DIM 8192
#define M_DIM 2048
#define NT_KV 32   // M_DIM / 64 KV tiles

typedef unsigned short u16;
typedef unsigned int u32;
typedef short bf16x8 __attribute__((ext_vector_type(8)));
typedef float f32x4 __attribute__((ext_vector_type(4)));
typedef float f32x16 __attribute__((ext_vector_type(16)));
typedef u32 u32x4 __attribute__((ext_vector_type(4)));

__device__ inline u16 f2bf(float f) {
  u32 u = __builtin_bit_cast(u32, f);
  u += 0x7fffu + ((u >> 16) & 1u);  // RNE, finite inputs
  return (u16)(u >> 16);
}
__device__ inline u32 cvtpk_bf16(float lo, float hi) {
  u32 r;
  asm("v_cvt_pk_bf16_f32 %0, %1, %2" : "=v"(r) : "v"(lo), "v"(hi));
  return r;
}

// ---------------- Projections: Y = W @ X_b, MFMA 16x16x32 ----------------
// MODE 0: Qt bf16 [b][x][o]; MODE 1: skip f32 [b][o][x] (d_out);
// MODE 2: K frag-major; MODE 3: V frag-major (both linear-copy stageable).
template <int MODE>
__device__ inline void proj_pass(const float* __restrict__ W, float wscale,
                                 const u16* __restrict__ xt_s,
                                 float* __restrict__ outf, u16* __restrict__ outh,
                                 int b, int X, int x0, int t) {
  const int l = t & 63, w = t >> 6, lr = l & 15, lh = (l >> 4) & 3;
  bf16x8 wf[2][4];
  #pragma unroll
  for (int ot = 0; ot < 2; ++ot)
    #pragma unroll
    for (int kc = 0; kc < 4; ++kc) {
      const float* wp = &W[(size_t)(w * 32 + ot * 16 + lr) * 128 + kc * 32 + lh * 8];
      float4 a0 = *(const float4*)wp;
      float4 a1 = *(const float4*)(wp + 4);
      bf16x8 f;
      f[0] = (short)f2bf(a0.x * wscale); f[1] = (short)f2bf(a0.y * wscale);
      f[2] = (short)f2bf(a0.z * wscale); f[3] = (short)f2bf(a0.w * wscale);
      f[4] = (short)f2bf(a1.x * wscale); f[5] = (short)f2bf(a1.y * wscale);
      f[6] = (short)f2bf(a1.z * wscale); f[7] = (short)f2bf(a1.w * wscale);
      wf[ot][kc] = f;
    }
  f32x4 acc[2][4];
  #pragma unroll
  for (int ot = 0; ot < 2; ++ot)
    #pragma unroll
    for (int xt = 0; xt < 4; ++xt) acc[ot][xt] = 0.f;

  #pragma unroll
  for (int xt = 0; xt < 4; ++xt) {
    int xx = xt * 16 + lr;
    #pragma unroll
    for (int kc = 0; kc < 4; ++kc) {
      bf16x8 bf = *(const bf16x8*)&xt_s[xx * 128 + ((kc * 32 + lh * 8) ^ ((xx & 15) << 3))];
      #pragma unroll
      for (int ot = 0; ot < 2; ++ot)
        acc[ot][xt] = __builtin_amdgcn_mfma_f32_16x16x32_bf16(wf[ot][kc], bf, acc[ot][xt], 0, 0, 0);
    }
  }
  #pragma unroll
  for (int ot = 0; ot < 2; ++ot) {
    int o0 = w * 32 + ot * 16 + lh * 4;
    #pragma unroll
    for (int xt = 0; xt < 4; ++xt) {
      int xg = x0 + xt * 16 + lr;
      if constexpr (MODE == 0) {
        u16 h[4];
        #pragma unroll
        for (int r = 0; r < 4; ++r) h[r] = f2bf(acc[ot][xt][r]);
        *(uint2*)&outh[((size_t)b * X + xg) * 128 + o0] = *(uint2*)h;
      } else if constexpr (MODE == 1) {
        #pragma unroll
        for (int r = 0; r < 4; ++r)
          outf[((size_t)b * 128 + o0 + r) * X + xg] = acc[ot][xt][r];
      } else if constexpr (MODE == 2) {
        int tt = xg >> 6, mt = (xg >> 5) & 1, ms = xg & 31;
        int kcK = o0 >> 4, lh1p = (o0 >> 3) & 1, e0 = o0 & 7;
        u16 h[4];
        #pragma unroll
        for (int r = 0; r < 4; ++r) h[r] = f2bf(acc[ot][xt][r]);
        size_t off = ((((size_t)(b * NT_KV + tt) * 2 + mt) * 8 + kcK) * 64 + (ms | (lh1p << 5))) * 8 + e0;
        *(uint2*)&outh[off] = *(uint2*)h;
      } else {
        int tt = xg >> 6, sv = (xg >> 4) & 3, lh1m = (xg >> 3) & 1, e = xg & 7;
        int ctv = o0 >> 5;
        #pragma unroll
        for (int r = 0; r < 4; ++r) {
          int cs = (o0 + r) & 31;
          size_t off = ((((size_t)(b * NT_KV + tt) * 4 + ctv) * 4 + sv) * 64 + (cs | (lh1m << 5))) * 8 + e;
          outh[off] = f2bf(acc[ot][xt][r]);
        }
      }
    }
  }
}

template <int MODE_A, int MODE_B>
__global__ __launch_bounds__(256, 2) void proj_kernel(
    const float* __restrict__ in, const float* __restrict__ WA, const float* __restrict__ WB,
    float* __restrict__ fA, u16* __restrict__ hA, float* __restrict__ fB, u16* __restrict__ hB,
    int X, float wscaleA) {
  __shared__ u16 xt_s[64 * 128];
  const int b = blockIdx.y, x0 = blockIdx.x * 64, t = threadIdx.x;
  #pragma unroll
  for (int pp = 0; pp < 8; ++pp) {
    int c = pp * 16 + (t >> 4);
    int x4 = (t & 15) * 4;
    float4 v = *(const float4*)&in[((size_t)b * 128 + c) * X + x0 + x4];
    xt_s[(x4 + 0) * 128 + (c ^ (((x4 + 0) & 15) << 3))] = f2bf(v.x);
    xt_s[(x4 + 1) * 128 + (c ^ (((x4 + 1) & 15) << 3))] = f2bf(v.y);
    xt_s[(x4 + 2) * 128 + (c ^ (((x4 + 2) & 15) << 3))] = f2bf(v.z);
    xt_s[(x4 + 3) * 128 + (c ^ (((x4 + 3) & 15) << 3))] = f2bf(v.w);
  }
  __syncthreads();
  proj_pass<MODE_A>(WA, wscaleA, xt_s, fA, hA, b, X, x0, t);
  proj_pass<MODE_B>(WB, 1.0f, xt_s, fB, hB, b, X, x0, t);
}

// ---------------- Flash attention, 32x32x16, swapped QK^T ----------------
// 512 thr = 8 waves; waves 0-3 do KV tiles 0-15, waves 4-7 do 16-31
// (independent online softmax per group), f32 merge in-block at the end.
__device__ inline void stage_kv(const u16* __restrict__ gK, const u16* __restrict__ gV,
                                u16* lK, u16* lV, int tile, int tg) {
  const u16* ks = gK + (size_t)tile * 8192;
  const u16* vs = gV + (size_t)tile * 8192;
  #pragma unroll
  for (int i = 0; i < 4; ++i) {
    int ch = tg + i * 256;
    __builtin_amdgcn_global_load_lds((const __attribute__((address_space(1))) void*)(ks + ch * 8),
                                     (__attribute__((address_space(3))) void*)(lK + ch * 8), 16, 0, 0);
    __builtin_amdgcn_global_load_lds((const __attribute__((address_space(1))) void*)(vs + ch * 8),
                                     (__attribute__((address_space(3))) void*)(lV + ch * 8), 16, 0, 0);
  }
}

__global__ __launch_bounds__(512, 2) void attn_kernel(
    const u16* __restrict__ Qt, const u16* __restrict__ Kt2,
    const u16* __restrict__ Vp, float* __restrict__ out) {
  __shared__ union {
    u16 kv[2][2][2][8192];   // [grp][dbuf][K/V][8192 u16] = 128 KB
    float u2[4][4096];       // waves 4-7 raw O (64 KB), aliases retired kv
  } lds;
  __shared__ float mlbuf[4][2][64];

  const int bid = blockIdx.x;
  const int xcd = bid & 7, b = xcd & 3, slot = bid >> 3;  // batch pinned per XCD pair
  const int n0 = ((xcd >> 2) * 32 + slot) * 128;
  const int t = threadIdx.x, w = t >> 6, l = t & 63, lh1 = l >> 5;
  const int g = w >> 2;        // KV-half group
  const int tg = t & 255;      // group-local thread id
  const int nq = n0 + (w & 3) * 32 + (l & 31);

  // Q fragments (B[k=c][j=q]): q = l&31, c = kc*16 + lh1*8 + e
  bf16x8 qf[8];
  #pragma unroll
  for (int kc = 0; kc < 8; ++kc)
    qf[kc] = *(const bf16x8*)&Qt[((size_t)b * N_DIM + nq) * 128 + kc * 16 + lh1 * 8];

  const u16* gK = Kt2 + (size_t)b * NT_KV * 8192;
  const u16* gV = Vp + (size_t)b * NT_KV * 8192;
  const int t0 = g * 16;

  f32x16 acco[4];
  #pragma unroll
  for (int ct = 0; ct < 4; ++ct) acco[ct] = 0.f;
  float mrun = -INFINITY, lrun = 0.f;

  stage_kv(gK, gV, &lds.kv[g][0][0][0], &lds.kv[g][0][1][0], t0, tg);
  __syncthreads();
  int cur = 0;
  for (int i = 0; i < 16; ++i) {
    if (i + 1 < 16)
      stage_kv(gK, gV, &lds.kv[g][cur ^ 1][0][0], &lds.kv[g][cur ^ 1][1][0], t0 + i + 1, tg);
    const u16* lK = &lds.kv[g][cur][0][0];
    const u16* lV = &lds.kv[g][cur][1][0];

    // S[m][q] = sum_c K[m][c] Q[q][c]; lane-linear frag reads
    f32x16 sacc[2];
    sacc[0] = 0.f; sacc[1] = 0.f;
    __builtin_amdgcn_s_setprio(1);
    #pragma unroll
    for (int kc = 0; kc < 8; ++kc)
      #pragma unroll
      for (int mt = 0; mt < 2; ++mt) {
        bf16x8 kf = *(const bf16x8*)&lK[((mt * 8 + kc) * 64 + l) * 8];
        sacc[mt] = __builtin_amdgcn_mfma_f32_32x32x16_bf16(kf, qf[kc], sacc[mt], 0, 0, 0);
      }
    __builtin_amdgcn_s_setprio(0);

    // Online softmax: lane holds 32 of 64 m for q=l&31; partner l^32 the rest.
    float pm = sacc[0][0];
    #pragma unroll
    for (int mt = 0; mt < 2; ++mt)
      #pragma unroll
      for (int r = 0; r < 16; ++r) pm = fmaxf(pm, sacc[mt][r]);
    pm = fmaxf(pm, __shfl_xor(pm, 32, 64));
    if (!__all(pm <= mrun + 11.0f)) {   // defer-max (T13)
      float mn = fmaxf(mrun, pm);
      float sc = exp2f(mrun - mn);
      lrun *= sc;
      #pragma unroll
      for (int ct = 0; ct < 4; ++ct)
        #pragma unroll
        for (int r = 0; r < 16; ++r) acco[ct][r] *= sc;
      mrun = mn;
    }
    float p[2][16];
    float rs = 0.f;
    #pragma unroll
    for (int mt = 0; mt < 2; ++mt)
      #pragma unroll
      for (int r = 0; r < 16; ++r) {
        p[mt][r] = exp2f(sacc[mt][r] - mrun);
        rs += p[mt][r];
      }
    rs += __shfl_xor(rs, 32, 64);
    lrun += rs;

    // Pack P; exchange halves so B-frag gets m = s*16 + 8*lh1 + e
    u32 gpk[8][2];
    #pragma unroll
    for (int mt = 0; mt < 2; ++mt)
      #pragma unroll
      for (int j = 0; j < 4; ++j) {
        gpk[mt * 4 + j][0] = cvtpk_bf16(p[mt][j * 4 + 0], p[mt][j * 4 + 1]);
        gpk[mt * 4 + j][1] = cvtpk_bf16(p[mt][j * 4 + 2], p[mt][j * 4 + 3]);
      }
    #pragma unroll
    for (int s = 0; s < 4; ++s) {
      const int ga = (s >> 1) * 4 + (s & 1) * 2, gb = ga + 1;
      u32 s0 = lh1 ? gpk[ga][0] : gpk[gb][0];
      u32 s1 = lh1 ? gpk[ga][1] : gpk[gb][1];
      u32 r0 = (u32)__shfl_xor((int)s0, 32, 64);
      u32 r1 = (u32)__shfl_xor((int)s1, 32, 64);
      u32x4 fv;
      fv.x = lh1 ? r0 : gpk[ga][0];
      fv.y = lh1 ? r1 : gpk[ga][1];
      fv.z = lh1 ? gpk[gb][0] : r0;
      fv.w = lh1 ? gpk[gb][1] : r1;
      bf16x8 pf = __builtin_bit_cast(bf16x8, fv);
      __builtin_amdgcn_s_setprio(1);
      #pragma unroll
      for (int ct = 0; ct < 4; ++ct) {
        bf16x8 vf = *(const bf16x8*)&lV[((ct * 4 + s) * 64 + l) * 8];
        acco[ct] = __builtin_amdgcn_mfma_f32_32x32x16_bf16(vf, pf, acco[ct], 0, 0, 0);
      }
      __builtin_amdgcn_s_setprio(0);
    }
    __syncthreads();  // drains prefetch + protects dbuf swap (both groups in lockstep)
    cur ^= 1;
  }

  // In-block merge of the two KV halves (exact f32).
  if (w >= 4) {
    float* dst = lds.u2[w - 4];
    #pragma unroll
    for (int ct = 0; ct < 4; ++ct)
      #pragma unroll
      for (int r = 0; r < 16; ++r) dst[(ct * 16 + r) * 64 + l] = acco[ct][r];
    mlbuf[w - 4][0][l] = mrun;
    mlbuf[w - 4][1][l] = lrun;
  }
  __syncthreads();
  if (w < 4) {
    float m2 = mlbuf[w][0][l], l2 = mlbuf[w][1][l];
    float M = fmaxf(mrun, m2);
    float a1 = exp2f(mrun - M), a2 = exp2f(m2 - M);
    float inv = 1.0f / (lrun * a1 + l2 * a2);
    a1 *= inv; a2 *= inv;
    const float* src = lds.u2[w];
    #pragma unroll
    for (int ct = 0; ct < 4; ++ct)
      #pragma unroll
      for (int r = 0; r < 16; ++r) {
        int c = ct * 32 + (r & 3) + 8 * ((r >> 2) & 3) + 4 * lh1;
        float val = acco[ct][r] * a1 + src[(ct * 16 + r) * 64 + l] * a2;
        out[((size_t)b * 128 + c) * N_DIM + nq] += val;
      }
  }
}

extern "C" void kernel_launch(void* const* d_in, const int* in_sizes, int n_in,
                              void* d_out, int out_size, void* d_ws, size_t ws_size,
                              hipStream_t stream) {
  const float* up    = (const float*)d_in[0];
  const float* down  = (const float*)d_in[1];
  const float* wq    = (const float*)d_in[2];
  const float* wk    = (const float*)d_in[3];
  const float* wv    = (const float*)d_in[4];
  const float* wskip = (const float*)d_in[5];
  float* out = (float*)d_out;

  u16* Qt  = (u16*)d_ws;                                   // 8 MB  [b][n][c]
  u16* Kt2 = Qt + (size_t)B_DIM * N_DIM * C_DIM;           // 2 MB  frag-major
  u16* Vp  = Kt2 + (size_t)B_DIM * M_DIM * C_DIM;          // 2 MB  frag-major

  const float qscale = (float)(1.4426950408889634 / sqrt(128.0));  // log2e/sqrt(C)

  hipLaunchKernelGGL((proj_kernel<0, 1>), dim3(N_DIM / 64, B_DIM), dim3(256), 0, stream,
                     up, wq, wskip, nullptr, Qt, out, nullptr, N_DIM, qscale);
  hipLaunchKernelGGL((proj_kernel<2, 3>), dim3(M_DIM / 64, B_DIM), dim3(256), 0, stream,
                     down, wk, wv, nullptr, Kt2, nullptr, Vp, M_DIM, 1.0f);
  hipLaunchKernelGGL((attn_kernel), dim3(256), dim3(512), 0, stream,
                     Qt, Kt2, Vp, out);
}